// Round 1
// baseline (435.717 us; speedup 1.0000x reference)
//
#include <hip/hip_runtime.h>

// RoiAlign (TF crop_and_resize, bilinear, extrapolation_value=0)
// boxes: [B, N, 4] f32 pixel coords (x1, y1, x2, y2)
// fpn:   [B, H, W, C] f32 (NHWC, C innermost)
// out:   [B, N, 14, 14, C] f32
constexpr int CROP_H = 14;
constexpr int CROP_W = 14;
constexpr int B = 4, N = 256, H = 256, W = 256, C = 256;

__global__ __launch_bounds__(256) void roi_align_kernel(
    const float* __restrict__ boxes,
    const float* __restrict__ fpn,
    float* __restrict__ out) {
  // One 64-lane wave per output position (b,n,i,j); lane covers 4 channels (float4).
  const int wave = threadIdx.x >> 6;
  const int lane = threadIdx.x & 63;
  int pos = blockIdx.x * 4 + wave;   // [0, B*N*CROP_H*CROP_W)

  int j = pos % CROP_W;
  int t = pos / CROP_W;
  int i = t % CROP_H;
  t /= CROP_H;
  int n = t % N;
  int b = t / N;

  const float* bx = boxes + (size_t)(b * N + n) * 4;
  float x1 = bx[0], y1 = bx[1], x2 = bx[2], y2 = bx[3];

  // Replicate the reference's exact fp32 normalization sequence to keep
  // absmax at rounding level.
  const float Hf = (float)H, Wf = (float)W;
  float ny1 = y1 / Hf * Hf / (Hf - 1.0f);
  float nx1 = x1 / Wf * Wf / (Wf - 1.0f);
  float ny2 = (y2 / Hf * Hf - 1.0f) / (Hf - 1.0f);
  float nx2 = (x2 / Wf * Wf - 1.0f) / (Wf - 1.0f);

  float ty = (float)i / (float)(CROP_H - 1);
  float tx = (float)j / (float)(CROP_W - 1);
  float ys = (ny1 + (ny2 - ny1) * ty) * (Hf - 1.0f);
  float xs = (nx1 + (nx2 - nx1) * tx) * (Wf - 1.0f);

  bool valid = (ys >= 0.0f) && (ys <= Hf - 1.0f) &&
               (xs >= 0.0f) && (xs <= Wf - 1.0f);

  float y0f = floorf(ys), x0f = floorf(xs);
  float wy = ys - y0f, wx = xs - x0f;
  int y0  = (int)fminf(fmaxf(y0f,        0.0f), Hf - 1.0f);
  int y1i = (int)fminf(fmaxf(y0f + 1.0f, 0.0f), Hf - 1.0f);
  int x0  = (int)fminf(fmaxf(x0f,        0.0f), Wf - 1.0f);
  int x1i = (int)fminf(fmaxf(x0f + 1.0f, 0.0f), Wf - 1.0f);

  const float4* f4 = (const float4*)fpn;
  const int C4 = C >> 2;  // 64 float4 per pixel; lane i takes float4 #i
  int rb = b * H;
  size_t i00 = (size_t)((rb + y0)  * W + x0)  * C4 + lane;
  size_t i01 = (size_t)((rb + y0)  * W + x1i) * C4 + lane;
  size_t i10 = (size_t)((rb + y1i) * W + x0)  * C4 + lane;
  size_t i11 = (size_t)((rb + y1i) * W + x1i) * C4 + lane;

  float4 tl = f4[i00];
  float4 tr = f4[i01];
  float4 bl = f4[i10];
  float4 br = f4[i11];

  float w00 = (1.0f - wy) * (1.0f - wx);
  float w01 = (1.0f - wy) * wx;
  float w10 = wy * (1.0f - wx);
  float w11 = wy * wx;

  float4 o;
  o.x = tl.x * w00 + tr.x * w01 + bl.x * w10 + br.x * w11;
  o.y = tl.y * w00 + tr.y * w01 + bl.y * w10 + br.y * w11;
  o.z = tl.z * w00 + tr.z * w01 + bl.z * w10 + br.z * w11;
  o.w = tl.w * w00 + tr.w * w01 + bl.w * w10 + br.w * w11;
  if (!valid) { o.x = 0.0f; o.y = 0.0f; o.z = 0.0f; o.w = 0.0f; }

  float4* out4 = (float4*)out;
  out4[(size_t)pos * C4 + lane] = o;
}

extern "C" void kernel_launch(void* const* d_in, const int* in_sizes, int n_in,
                              void* d_out, int out_size, void* d_ws, size_t ws_size,
                              hipStream_t stream) {
  const float* boxes = (const float*)d_in[0];  // [B, N, 4]
  const float* fpn   = (const float*)d_in[1];  // [B, H, W, C]
  float* out = (float*)d_out;                  // [B, N, 14, 14, C]

  const int positions = B * N * CROP_H * CROP_W;  // 200704, divisible by 4
  dim3 grid(positions / 4), block(256);
  hipLaunchKernelGGL(roi_align_kernel, grid, block, 0, stream, boxes, fpn, out);
}

// Round 3
// 433.796 us; speedup vs baseline: 1.0044x; 1.0044x over previous
//
#include <hip/hip_runtime.h>

// RoiAlign (TF crop_and_resize, bilinear, extrapolation_value=0)
// boxes: [B, N, 4] f32 pixel coords (x1, y1, x2, y2)
// fpn:   [B, H, W, C] f32 (NHWC, C innermost)
// out:   [B, N, 14, 14, C] f32
//
// R1/R2: output stores made non-temporal. fpn (256 MB) == L3 capacity;
// cacheable stores were evicting it, forcing the ~3.2x cross-box re-reads
// (822 MB issued vs 256 MB distinct) out to HBM. nt stores keep fpn
// L3-resident. R2 fix: use a native clang vector type for the nt builtin
// (HIP_vector_type<float,4> is rejected).
constexpr int CROP_H = 14;
constexpr int CROP_W = 14;
constexpr int B = 4, N = 256, H = 256, W = 256, C = 256;

typedef float vfloat4 __attribute__((ext_vector_type(4)));

__global__ __launch_bounds__(256) void roi_align_kernel(
    const float* __restrict__ boxes,
    const float* __restrict__ fpn,
    float* __restrict__ out) {
  // One 64-lane wave per output position (b,n,i,j); lane covers 4 channels (float4).
  const int wave = threadIdx.x >> 6;
  const int lane = threadIdx.x & 63;
  int pos = blockIdx.x * 4 + wave;   // [0, B*N*CROP_H*CROP_W)

  int j = pos % CROP_W;
  int t = pos / CROP_W;
  int i = t % CROP_H;
  t /= CROP_H;
  int n = t % N;
  int b = t / N;

  const float* bx = boxes + (size_t)(b * N + n) * 4;
  float x1 = bx[0], y1 = bx[1], x2 = bx[2], y2 = bx[3];

  // Replicate the reference's exact fp32 normalization sequence to keep
  // absmax at rounding level.
  const float Hf = (float)H, Wf = (float)W;
  float ny1 = y1 / Hf * Hf / (Hf - 1.0f);
  float nx1 = x1 / Wf * Wf / (Wf - 1.0f);
  float ny2 = (y2 / Hf * Hf - 1.0f) / (Hf - 1.0f);
  float nx2 = (x2 / Wf * Wf - 1.0f) / (Wf - 1.0f);

  float ty = (float)i / (float)(CROP_H - 1);
  float tx = (float)j / (float)(CROP_W - 1);
  float ys = (ny1 + (ny2 - ny1) * ty) * (Hf - 1.0f);
  float xs = (nx1 + (nx2 - nx1) * tx) * (Wf - 1.0f);

  bool valid = (ys >= 0.0f) && (ys <= Hf - 1.0f) &&
               (xs >= 0.0f) && (xs <= Wf - 1.0f);

  float y0f = floorf(ys), x0f = floorf(xs);
  float wy = ys - y0f, wx = xs - x0f;
  int y0  = (int)fminf(fmaxf(y0f,        0.0f), Hf - 1.0f);
  int y1i = (int)fminf(fmaxf(y0f + 1.0f, 0.0f), Hf - 1.0f);
  int x0  = (int)fminf(fmaxf(x0f,        0.0f), Wf - 1.0f);
  int x1i = (int)fminf(fmaxf(x0f + 1.0f, 0.0f), Wf - 1.0f);

  const float4* f4 = (const float4*)fpn;
  const int C4 = C >> 2;  // 64 float4 per pixel; lane i takes float4 #i
  int rb = b * H;
  size_t i00 = (size_t)((rb + y0)  * W + x0)  * C4 + lane;
  size_t i01 = (size_t)((rb + y0)  * W + x1i) * C4 + lane;
  size_t i10 = (size_t)((rb + y1i) * W + x0)  * C4 + lane;
  size_t i11 = (size_t)((rb + y1i) * W + x1i) * C4 + lane;

  float4 tl = f4[i00];
  float4 tr = f4[i01];
  float4 bl = f4[i10];
  float4 br = f4[i11];

  float w00 = (1.0f - wy) * (1.0f - wx);
  float w01 = (1.0f - wy) * wx;
  float w10 = wy * (1.0f - wx);
  float w11 = wy * wx;

  vfloat4 o;
  o.x = tl.x * w00 + tr.x * w01 + bl.x * w10 + br.x * w11;
  o.y = tl.y * w00 + tr.y * w01 + bl.y * w10 + br.y * w11;
  o.z = tl.z * w00 + tr.z * w01 + bl.z * w10 + br.z * w11;
  o.w = tl.w * w00 + tr.w * w01 + bl.w * w10 + br.w * w11;
  if (!valid) { o.x = 0.0f; o.y = 0.0f; o.z = 0.0f; o.w = 0.0f; }

  // Non-temporal store: don't let the 205 MB output stream evict fpn from L3.
  vfloat4* dst = (vfloat4*)out + (size_t)pos * C4 + lane;
  __builtin_nontemporal_store(o, dst);
}

extern "C" void kernel_launch(void* const* d_in, const int* in_sizes, int n_in,
                              void* d_out, int out_size, void* d_ws, size_t ws_size,
                              hipStream_t stream) {
  const float* boxes = (const float*)d_in[0];  // [B, N, 4]
  const float* fpn   = (const float*)d_in[1];  // [B, H, W, C]
  float* out = (float*)d_out;                  // [B, N, 14, 14, C]

  const int positions = B * N * CROP_H * CROP_W;  // 200704, divisible by 4
  dim3 grid(positions / 4), block(256);
  hipLaunchKernelGGL(roi_align_kernel, grid, block, 0, stream, boxes, fpn, out);
}